// Round 6
// baseline (16.157 us; speedup 1.0000x reference)
//
#include <hip/hip_runtime.h>

#define BATCH  128
#define NB     14
#define TS     1096
#define LTOT   24
#define OUTLEN 15367          // (NB-1)*TS + TS + LTOT - 1
#define XLEN   (NB * TS)      // 15344 (flat x per batch)
#define BS     128
#define TILE   256            // outputs per block (2 per thread)

// Flat formulation: out[b,o] = sum_{j=0..23} xflat[b,o-j] * h[b,(o-j)/TS, j]
// (taps outside [0, XLEN) contribute 0). Equivalent to per-frame conv +
// overlap_add because hop == per-frame x length == TS.
__global__ __launch_bounds__(BS)
void atc_flat_lds2(const float* __restrict__ x,
                   const float* __restrict__ h,
                   float* __restrict__ out) {
    const int b   = blockIdx.y;
    const int o0  = blockIdx.x * TILE;
    const int tid = threadIdx.x;

    __shared__ __align__(16) float xs[TILE + 32];   // xs[k] = xflat[o0-32+k]
    const float* __restrict__ xb = x + (size_t)b * XLEN;

    // ---- stage 288 floats = 72 float4 (zero-pad out-of-range) ----
    if (tid < (TILE + 32) / 4) {
        const int g = o0 - 32 + 4 * tid;            // 16B-aligned
        float4 v;
        if (g >= 0 && g + 4 <= XLEN) {
            v = *(const float4*)(xb + g);
        } else {
            v.x = ((unsigned)(g + 0) < (unsigned)XLEN) ? xb[g + 0] : 0.f;
            v.y = ((unsigned)(g + 1) < (unsigned)XLEN) ? xb[g + 1] : 0.f;
            v.z = ((unsigned)(g + 2) < (unsigned)XLEN) ? xb[g + 2] : 0.f;
            v.w = ((unsigned)(g + 3) < (unsigned)XLEN) ? xb[g + 3] : 0.f;
        }
        *(float4*)(&xs[4 * tid]) = v;
    }
    __syncthreads();

    // ---- sliding window: xw[m] = xflat[o_t - 24 + m], m = 0..27 ----
    // base xs index = 2*tid + 8 (even -> 8B-aligned ds_read_b64 x14)
    float xw[28];
    #pragma unroll
    for (int q = 0; q < 14; ++q) {
        float2 v = *(const float2*)(&xs[2 * tid + 8 + 2 * q]);
        xw[2*q] = v.x; xw[2*q+1] = v.y;
    }

    const int o_t = o0 + 2 * tid;                   // first output of thread
    float acc0 = 0.f, acc1 = 0.f;

    // per-thread frame span of valid taps
    int pl = o_t - 23; if (pl < 0) pl = 0;
    int ph = o_t + 1;  if (ph > XLEN - 1) ph = XLEN - 1;
    const int fl = pl / TS;                         // magic-mul (TS const)
    const int fh = ph / TS;

    if (fl == fh) {
        // 99% of threads: single h-row, fully unrolled
        const float* hr = h + ((size_t)b * NB + fh) * LTOT;  // 96B rows, 16B aligned
        float hw[LTOT];
        #pragma unroll
        for (int q = 0; q < 6; ++q) {
            float4 v = *(const float4*)(hr + 4 * q);
            hw[4*q] = v.x; hw[4*q+1] = v.y; hw[4*q+2] = v.z; hw[4*q+3] = v.w;
        }
        #pragma unroll
        for (int j = 0; j < LTOT; ++j) {
            acc0 = fmaf(hw[j], xw[24 - j], acc0);
            acc1 = fmaf(hw[j], xw[25 - j], acc1);
        }
    } else {
        // window straddles a frame boundary (~1% of threads): per-tap h row
        const float* hb = h + (size_t)b * NB * LTOT;
        #pragma unroll
        for (int j = 0; j < LTOT; ++j) {
            const int p0 = o_t - j;
            if ((unsigned)p0 < (unsigned)XLEN)
                acc0 = fmaf(hb[(p0 / TS) * LTOT + j], xw[24 - j], acc0);
            const int p1 = p0 + 1;
            if ((unsigned)p1 < (unsigned)XLEN)
                acc1 = fmaf(hb[(p1 / TS) * LTOT + j], xw[25 - j], acc1);
        }
    }

    float* ob = out + (size_t)b * OUTLEN + o_t;
    if (o_t < OUTLEN)     ob[0] = acc0;
    if (o_t + 1 < OUTLEN) ob[1] = acc1;
}

extern "C" void kernel_launch(void* const* d_in, const int* in_sizes, int n_in,
                              void* d_out, int out_size, void* d_ws, size_t ws_size,
                              hipStream_t stream) {
    const float* x = (const float*)d_in[0];   // [B, NB, TS] == [B, XLEN] flat
    const float* h = (const float*)d_in[1];   // [B, NB, LTOT]
    float* out = (float*)d_out;               // [B, OUTLEN]

    dim3 block(BS, 1, 1);
    dim3 grid((OUTLEN + TILE - 1) / TILE, BATCH, 1);   // (61, 128) = 7808 blocks
    atc_flat_lds2<<<grid, block, 0, stream>>>(x, h, out);
}

// Round 7
// 13.324 us; speedup vs baseline: 1.2126x; 1.2126x over previous
//
#include <hip/hip_runtime.h>

#define BATCH  128
#define NB     14
#define TS     1096
#define LTOT   24
#define OUTLEN 15367                       // (NB-1)*TS + TS + LTOT - 1
#define XLEN   (NB * TS)                   // 15344 (flat x per batch)
#define BS     256
#define TILE   256
#define NBI    ((OUTLEN + TILE - 1) / TILE)  // 61 tiles per batch
#define NBX    11
#define CHUNK  6                           // tiles per block (11*6 >= 61)

// async global->LDS DMA (width 16 / 4). LDS dest is wave-uniform base +
// lane*size; our lanes compute exactly base+lane*size, so layout matches.
__device__ __forceinline__ void dma16(const float* g, float* l) {
    __builtin_amdgcn_global_load_lds(
        (const __attribute__((address_space(1))) uint32_t*)g,
        (__attribute__((address_space(3))) uint32_t*)l, 16, 0, 0);
}
__device__ __forceinline__ void dma4(const float* g, float* l) {
    __builtin_amdgcn_global_load_lds(
        (const __attribute__((address_space(1))) uint32_t*)g,
        (__attribute__((address_space(3))) uint32_t*)l, 4, 0, 0);
}

// Flat formulation: out[b,o] = sum_{j=0..23} xflat[b,o-j] * h[b,(o-j)/TS, j]
// (taps outside [0, XLEN) contribute 0). Grid-stride persistent blocks:
// block (bx,b) processes tiles bi = bx*CHUNK .. min(+CHUNK, NBI) of batch b.
__global__ __launch_bounds__(BS)
void atc_persist(const float* __restrict__ x,
                 const float* __restrict__ h,
                 float* __restrict__ out) {
    const int b   = blockIdx.y;
    const int bx  = blockIdx.x;
    const int tid = threadIdx.x;

    const float* __restrict__ xb = x + (size_t)b * XLEN;
    const float* __restrict__ hb = h + (size_t)b * NB * LTOT;
    float* __restrict__ ob = out + (size_t)b * OUTLEN;

    __shared__ __align__(16) float xs[2][TILE + 32];  // xs[c][k]=xflat[bi*TILE-32+k]

    const int bi0 = bx * CHUNK;
    const int biN = (bi0 + CHUNK < NBI) ? bi0 + CHUNK : NBI;

    // stage tile bi into buffer c (zero-padded at array edges)
    auto stage = [&](int bi, int c) {
        const int g0 = bi * TILE - 32;
        if (bi >= 1 && bi <= 58) {                   // interior: async DMA
            if (tid < 64)      dma16(xb + g0 + 32 + 4 * tid, &xs[c][32 + 4 * tid]);
            else if (tid < 96) dma4 (xb + g0 + (tid - 64),   &xs[c][tid - 64]);
        } else {                                      // edge: guarded VGPR path
            if (tid < 72) {
                const int g = g0 + 4 * tid;
                float4 v;
                if (g >= 0 && g + 4 <= XLEN) {
                    v = *(const float4*)(xb + g);
                } else {
                    v.x = ((unsigned)(g+0) < (unsigned)XLEN) ? xb[g+0] : 0.f;
                    v.y = ((unsigned)(g+1) < (unsigned)XLEN) ? xb[g+1] : 0.f;
                    v.z = ((unsigned)(g+2) < (unsigned)XLEN) ? xb[g+2] : 0.f;
                    v.w = ((unsigned)(g+3) < (unsigned)XLEN) ? xb[g+3] : 0.f;
                }
                *(float4*)(&xs[c][4 * tid]) = v;
            }
        }
    };

    stage(bi0, 0);

    int c = 0;
    for (int bi = bi0; bi < biN; ++bi, c ^= 1) {
        __syncthreads();                    // drains DMA (vmcnt) + ds_writes
        if (bi + 1 < biN) stage(bi + 1, c ^ 1);   // overlap next stage w/ compute

        const int o0 = bi * TILE;
        const int o  = o0 + tid;

        int pa = o0 - 23;        if (pa < 0) pa = 0;
        int pb = o0 + TILE - 1;  if (pb > XLEN - 1) pb = XLEN - 1;
        const int fa = pa / TS;             // magic-mul (TS compile-time)
        const int fb = pb / TS;             // fa or fa+1

        float hwA[LTOT];
        {
            const float* hr = hb + fa * LTOT;       // 96B rows, 16B aligned
            #pragma unroll
            for (int q = 0; q < 6; ++q) {
                float4 v = *(const float4*)(hr + 4 * q);
                hwA[4*q]=v.x; hwA[4*q+1]=v.y; hwA[4*q+2]=v.z; hwA[4*q+3]=v.w;
            }
        }

        float acc = 0.f;
        if (fa == fb) {
            #pragma unroll
            for (int j = 0; j < LTOT; ++j)
                acc = fmaf(hwA[j], xs[c][32 + tid - j], acc);
        } else {
            float hwB[LTOT];
            {
                const float* hr = hb + fb * LTOT;
                #pragma unroll
                for (int q = 0; q < 6; ++q) {
                    float4 v = *(const float4*)(hr + 4 * q);
                    hwB[4*q]=v.x; hwB[4*q+1]=v.y; hwB[4*q+2]=v.z; hwB[4*q+3]=v.w;
                }
            }
            const int sB = fb * TS;
            #pragma unroll
            for (int j = 0; j < LTOT; ++j) {
                const float hv = (o - j >= sB) ? hwB[j] : hwA[j];
                acc = fmaf(hv, xs[c][32 + tid - j], acc);
            }
        }

        if (o < OUTLEN) ob[o] = acc;
        // buffer safety: reads of xs[c] finish before each wave reaches the
        // next top-of-loop barrier; writes to xs[c] resume only after it.
    }
}

extern "C" void kernel_launch(void* const* d_in, const int* in_sizes, int n_in,
                              void* d_out, int out_size, void* d_ws, size_t ws_size,
                              hipStream_t stream) {
    const float* x = (const float*)d_in[0];   // [B, NB, TS] == [B, XLEN] flat
    const float* h = (const float*)d_in[1];   // [B, NB, LTOT]
    float* out = (float*)d_out;               // [B, OUTLEN]

    dim3 block(BS, 1, 1);
    dim3 grid(NBX, BATCH, 1);                 // (11, 128) = 1408 workgroups
    atc_persist<<<grid, block, 0, stream>>>(x, h, out);
}

// Round 8
// 11.913 us; speedup vs baseline: 1.3562x; 1.1184x over previous
//
#include <hip/hip_runtime.h>

#define BATCH  128
#define NB     14
#define TS     1096
#define LTOT   24
#define FRAME  (TS + LTOT - 1)            // 1119
#define OUTLEN ((NB - 1) * TS + FRAME)    // 15367
#define XLEN   (NB * TS)                  // 15344 (flat x per batch)
#define BS     256

// Flat formulation: out[b,o] = sum_{j=0..23} xflat[b,o-j] * h[b,(o-j)/TS, j]
// (taps outside [0, XLEN) contribute 0). Equivalent to per-frame conv +
// overlap_add because hop == per-frame x length == TS.
//
// Block = 256 consecutive outputs of one batch. Taps for the block span
// [o0-23, o0+255] (279 positions < TS) -> at most 2 h-rows per block.
// R4 structure — best measured (11.9 us); reverted verbatim for reproduction.
__global__ __launch_bounds__(256)
void atc_lds_kernel(const float* __restrict__ x,
                    const float* __restrict__ h,
                    float* __restrict__ out) {
    const int b   = blockIdx.y;
    const int o0  = blockIdx.x * BS;
    const int tid = threadIdx.x;
    const int o   = o0 + tid;

    __shared__ __align__(16) float xs[BS + 32];   // xs[k] = xflat[b, o0-32+k]
    const float* __restrict__ xb = x + (size_t)b * XLEN;

    // ---- stage 288 floats (72 float4), zero-padding out-of-range ----
    if (tid < 72) {
        const int g = o0 - 32 + 4 * tid;          // 16B-aligned global offset
        const float* gp = xb + g;
        float4 v;
        if (g >= 0 && g + 4 <= XLEN) {
            v = *(const float4*)gp;
        } else {
            v.x = ((unsigned)(g + 0) < (unsigned)XLEN) ? gp[0] : 0.f;
            v.y = ((unsigned)(g + 1) < (unsigned)XLEN) ? gp[1] : 0.f;
            v.z = ((unsigned)(g + 2) < (unsigned)XLEN) ? gp[2] : 0.f;
            v.w = ((unsigned)(g + 3) < (unsigned)XLEN) ? gp[3] : 0.f;
        }
        *(float4*)(&xs[4 * tid]) = v;
    }
    __syncthreads();

    // ---- frame span of this block's valid taps (block-uniform) ----
    int pa = o0 - 23;      if (pa < 0) pa = 0;
    int pb = o0 + BS - 1;  if (pb > XLEN - 1) pb = XLEN - 1;
    const int fa = pa / TS;                       // magic-mul, compile-time TS
    const int fb = pb / TS;                       // fb == fa or fa+1

    const float* __restrict__ hA = h + ((size_t)b * NB + fa) * LTOT;
    float hwA[LTOT];
    #pragma unroll
    for (int q = 0; q < 6; ++q) {
        float4 v = *(const float4*)(hA + 4 * q);  // 96B rows -> 16B aligned
        hwA[4*q] = v.x; hwA[4*q+1] = v.y; hwA[4*q+2] = v.z; hwA[4*q+3] = v.w;
    }

    float acc = 0.f;
    if (fa == fb) {
        // fast path: single h-row, conflict-free LDS reads, all unrolled
        #pragma unroll
        for (int j = 0; j < LTOT; ++j)
            acc = fmaf(hwA[j], xs[32 + tid - j], acc);
    } else {
        // seam block: per-tap select between the two register h-rows
        const float* __restrict__ hB = h + ((size_t)b * NB + fb) * LTOT;
        float hwB[LTOT];
        #pragma unroll
        for (int q = 0; q < 6; ++q) {
            float4 v = *(const float4*)(hB + 4 * q);
            hwB[4*q] = v.x; hwB[4*q+1] = v.y; hwB[4*q+2] = v.z; hwB[4*q+3] = v.w;
        }
        const int sB = fb * TS;
        #pragma unroll
        for (int j = 0; j < LTOT; ++j) {
            const float hv = (o - j >= sB) ? hwB[j] : hwA[j];
            acc = fmaf(hv, xs[32 + tid - j], acc);
        }
    }

    if (o < OUTLEN)
        out[(size_t)b * OUTLEN + o] = acc;
}

extern "C" void kernel_launch(void* const* d_in, const int* in_sizes, int n_in,
                              void* d_out, int out_size, void* d_ws, size_t ws_size,
                              hipStream_t stream) {
    const float* x = (const float*)d_in[0];   // [B, NB, TS] == [B, XLEN] flat
    const float* h = (const float*)d_in[1];   // [B, NB, LTOT]
    float* out = (float*)d_out;               // [B, OUTLEN]

    dim3 block(BS, 1, 1);
    dim3 grid((OUTLEN + BS - 1) / BS, BATCH, 1);   // (61, 128) = 7808 blocks
    atc_lds_kernel<<<grid, block, 0, stream>>>(x, h, out);
}